// Round 15
// baseline (181.821 us; speedup 1.0000x reference)
//
#include <hip/hip_runtime.h>
#include <hip/hip_bf16.h>

#define B_ 128
#define S_ 196
#define E_ 768
#define M_ 768
#define KTOT (S_*E_)            // 150528
#define BK 256                  // k per superstep
#define SS_TOTAL (KTOT/BK)      // 588
#define KSPLIT 40
#define BN 64                   // m-rows per workgroup
#define MTN (M_/BN)             // 12
#define PITCH 520               // LDS row pitch: 130 words -> 2-way banks on b64 col reads
#define ZC 4                    // z-chunks in reduce

typedef __bf16 bf16x8 __attribute__((ext_vector_type(8)));
typedef __bf16 bf16x4 __attribute__((ext_vector_type(4)));
typedef float  f32x4  __attribute__((ext_vector_type(4)));
typedef float  f32x16 __attribute__((ext_vector_type(16)));

__device__ inline bf16x8 cvt8(const float* __restrict__ p) {
    float4 a = *(const float4*)p;
    float4 b = *(const float4*)(p + 4);
    bf16x8 r;
    r[0] = (__bf16)a.x; r[1] = (__bf16)a.y; r[2] = (__bf16)a.z; r[3] = (__bf16)a.w;
    r[4] = (__bf16)b.x; r[5] = (__bf16)b.y; r[6] = (__bf16)b.z; r[7] = (__bf16)b.w;
    return r;
}

// Barrier WITHOUT the implicit vmcnt(0) drain __syncthreads() carries.
__device__ inline void barrier_nodrain() {
    asm volatile("s_waitcnt lgkmcnt(0)" ::: "memory");
    __builtin_amdgcn_s_barrier();
}

// ---------------- prep: init_out | event_pool | pack_a (block-partitioned) ----
// pack_a: A f32 -> bf16 in 32x32x16 MFMA A-fragment order:
//   chunk c = ((ss*4 + bt)*16 + kf)*64 + lane  holds
//   A[bt*32 + (lane&31)][ss*256 + kf*16 + (lane>>5)*8 .. +8)
__global__ void prep(const float* __restrict__ mlp_b,
                     const float* __restrict__ fk_b,
                     const float* __restrict__ A,
                     const int* __restrict__ BE, int be_stride,
                     float* __restrict__ out,
                     float* __restrict__ EP,
                     __bf16* __restrict__ Apk) {
    const int bid = blockIdx.x;
    if (bid < 384) {
        int i = bid * 256 + threadIdx.x;
        int m = i % M_;
        out[i] = 0.9f * mlp_b[m] + 0.1f * fk_b[m];
    } else if (bid < 512) {
        int b = bid - 384;
        int s1 = BE[(b*4 + 0) * be_stride];
        int e1 = BE[(b*4 + 1) * be_stride];
        int s2 = BE[(b*4 + 2) * be_stride];
        int e2 = BE[(b*4 + 3) * be_stride];
        float inv1 = 1.0f / (float)(e1 - s1);
        float inv2 = 1.0f / (float)(e2 - s2);
        for (int c = threadIdx.x; c < E_; c += 256) {
            float sum1 = 0.f, sum2 = 0.f;
            for (int s = s1; s < e1; ++s) sum1 += A[((size_t)b * S_ + s) * E_ + c];
            for (int s = s2; s < e2; ++s) sum2 += A[((size_t)b * S_ + s) * E_ + c];
            EP[b * (2*E_) + c]       = sum1 * inv1;
            EP[b * (2*E_) + E_ + c]  = sum2 * inv2;
        }
    } else {
        const int nchunk = SS_TOTAL * 4 * 16 * 64;   // 2,408,448
        for (int c = (bid - 512) * 256 + threadIdx.x; c < nchunk; c += 3072 * 256) {
            int lane = c & 63;
            int kf   = (c >> 6) & 15;
            int bt   = (c >> 10) & 3;
            int ss   = c >> 12;
            int b = bt * 32 + (lane & 31);
            int k = ss * BK + kf * 16 + (lane >> 5) * 8;
            *(bf16x8*)(Apk + (size_t)c * 8) = cvt8(A + (size_t)b * KTOT + k);
        }
    }
}

// ---------------- fk_gemm: partial[kz][b][m] ------------------------------
// 4 waves, tile 128b x 64m x 256k/superstep, MFMA 32x32x16 (half the LDS
// bytes per FLOP of 16x16x32). Wave = 32b x 64m = 32 MFMA/ss.
// W staged 1KB-per-row float4 wave loads -> bf16 -> LDS rows (PITCH 520:
// 32-row column b64 reads are 2-way = free; 16B-aligned pitches are >=4-way).
// B-frag = 2 x ds_read_b64 concatenated. A register-direct from packed frags
// (512B single-segment loads, L2-resident via XCD pinning).
// Depth-1 W register prefetch + barrier_nodrain dbuf (proven R12 skeleton).
// Grid 480 = 60 wg/XCD = 5 kz x 12 mt pinned; LDS 65KB -> 2 wgs/CU.

#define LOAD_A(sl)                                                            \
    _Pragma("unroll")                                                         \
    for (int kf = 0; kf < 16; ++kf)                                           \
        aA[kf] = *(const bf16x8*)(abase + (size_t)(sl) * 32768 + kf * 512);

#define LOAD_W(sl)                                                            \
    _Pragma("unroll")                                                         \
    for (int i = 0; i < 16; ++i)                                              \
        w[i] = *(const float4*)(wbase + (size_t)i * KTOT + (size_t)(sl) * BK);

#define WRITE_W(buf)                                                          \
    _Pragma("unroll")                                                         \
    for (int i = 0; i < 16; ++i) {                                            \
        bf16x4 h;                                                             \
        h[0] = (__bf16)w[i].x; h[1] = (__bf16)w[i].y;                         \
        h[2] = (__bf16)w[i].z; h[3] = (__bf16)w[i].w;                         \
        *(bf16x4*)(&Wlds[buf][0] + wb + i * PITCH) = h;                       \
    }

#define COMPUTE(buf)                                                          \
    {                                                                         \
        const char* Wb = &Wlds[buf][0];                                       \
        _Pragma("unroll")                                                     \
        for (int kf = 0; kf < 16; ++kf) {                                     \
            int off0 = r32 * PITCH + kf * 32 + khalf * 16;                    \
            bf16x4 lo0 = *(const bf16x4*)(Wb + off0);                         \
            bf16x4 hi0 = *(const bf16x4*)(Wb + off0 + 8);                     \
            bf16x8 wf0 = __builtin_shufflevector(lo0, hi0, 0,1,2,3,4,5,6,7);  \
            acc0 = __builtin_amdgcn_mfma_f32_32x32x16_bf16(aA[kf], wf0,       \
                                                           acc0, 0, 0, 0);    \
            int off1 = off0 + 32 * PITCH;                                     \
            bf16x4 lo1 = *(const bf16x4*)(Wb + off1);                         \
            bf16x4 hi1 = *(const bf16x4*)(Wb + off1 + 8);                     \
            bf16x8 wf1 = __builtin_shufflevector(lo1, hi1, 0,1,2,3,4,5,6,7);  \
            acc1 = __builtin_amdgcn_mfma_f32_32x32x16_bf16(aA[kf], wf1,       \
                                                           acc1, 0, 0, 0);    \
        }                                                                     \
    }

__global__ __launch_bounds__(256, 2) void fk_gemm(const __bf16* __restrict__ Apk,
                                                  const float* __restrict__ W,
                                                  float* __restrict__ partial) {
    __shared__ __align__(16) char Wlds[2][BN * PITCH];  // 2 x 33,280 B

    const int wg   = blockIdx.x;        // 0..479
    const int xcd  = wg & 7;            // wg -> XCD round-robin (m09)
    const int slot = wg >> 3;           // 0..59 per-XCD sequence
    const int kz   = (slot / MTN) * 8 + xcd;  // 0..39, 5 kz groups per XCD
    const int mt   = slot % MTN;        // 0..11, dispatch-adjacent per kz
    const int ss0 = (SS_TOTAL * kz) / KSPLIT;
    const int SSN = (SS_TOTAL * (kz + 1)) / KSPLIT - ss0;   // 14 or 15

    const int tid = threadIdx.x;
    const int wv  = tid >> 6;           // 0..3 = 32-row b-quadrant
    const int lane = tid & 63;
    const int r32 = lane & 31;
    const int khalf = lane >> 5;

    const float*  wbase = W + (size_t)(mt * BN + wv * 16) * KTOT
                            + (size_t)ss0 * BK + lane * 4;
    const int     wb    = (wv * 16) * PITCH + lane * 8;
    const __bf16* abase = Apk + ((size_t)ss0 * 4 + wv) * 8192 + lane * 8;

    f32x16 acc0 = {}, acc1 = {};
    float4 w[16];
    bf16x8 aA[16];

    // prologue: stage ss0 into buf0; W(1) in flight
    LOAD_W(0)
    WRITE_W(0)
    LOAD_W(1)
    barrier_nodrain();

    int sl = 0;
    for (; sl + 1 < SSN; sl += 2) {
        // even: compute ss sl from buf0; stage W(sl+1) -> buf1
        LOAD_A(sl)
        COMPUTE(0)
        WRITE_W(1)                      // W(sl+1), loaded ~1 ss ago
        const bool more2 = (sl + 2 < SSN);
        if (more2) { LOAD_W(sl + 2) }
        barrier_nodrain();
        // odd: compute ss sl+1 from buf1; stage W(sl+2) -> buf0
        LOAD_A(sl + 1)
        COMPUTE(1)
        if (more2) {
            WRITE_W(0)                  // W(sl+2), loaded ~1 ss ago
            if (sl + 3 < SSN) { LOAD_W(sl + 3) }
            barrier_nodrain();
        }
    }
    if (SSN & 1) {  // leftover even ss in buf0 (written by last odd phase)
        LOAD_A(sl)
        COMPUTE(0)
    }

    // D layout 32x32 [m74/m101]: col = lane&31 (m),
    // row = (reg&3) + 8*(reg>>2) + 4*(lane>>5) (b)
    float* pz = partial + (size_t)kz * (B_ * M_);
#pragma unroll
    for (int reg = 0; reg < 16; ++reg) {
        const int b = wv * 32 + (reg & 3) + 8 * (reg >> 2) + 4 * khalf;
        pz[(size_t)b * M_ + mt * BN + r32]      = acc0[reg];
        pz[(size_t)b * M_ + mt * BN + 32 + r32] = acc1[reg];
    }
}

// ---------------- post: reduce_k | mlp_gemm (block-partitioned) -------------
__global__ __launch_bounds__(256) void post(const float* __restrict__ pp,
                                            const float* __restrict__ EP,
                                            const float* __restrict__ Wm,
                                            float* __restrict__ out) {
    const int bid = blockIdx.x;
    if (bid < 1536) {
        int t = bid * 256 + threadIdx.x;
        int i = t % (B_ * M_);
        int zc = t / (B_ * M_);
        float s = 0.f;
#pragma unroll
        for (int z = zc * (KSPLIT / ZC); z < (zc + 1) * (KSPLIT / ZC); ++z)
            s += pp[(size_t)z * (B_ * M_) + i];
        atomicAdd(out + i, 0.1f * s);
    } else {
        const int wid   = ((bid - 1536) * 256 + threadIdx.x) >> 6;  // 0..383
        const int lane  = threadIdx.x & 63;
        const int bt    = wid & 7;
        const int mt    = wid >> 3;
        const int row16 = lane & 15;
        const int kgrp  = lane >> 4;
        const float* Arow = EP + (size_t)(bt*16 + row16) * (2*E_);
        const float* Brow = Wm + (size_t)(mt*16 + row16) * (2*E_);
        f32x4 acc = {};
        for (int k0 = 0; k0 < 2*E_; k0 += 32) {
            bf16x8 af = cvt8(Arow + k0 + kgrp*8);
            bf16x8 bv = cvt8(Brow + k0 + kgrp*8);
            acc = __builtin_amdgcn_mfma_f32_16x16x32_bf16(af, bv, acc, 0, 0, 0);
        }
        const int m = mt*16 + row16;
#pragma unroll
        for (int r = 0; r < 4; ++r) {
            const int b = bt*16 + kgrp*4 + r;
            atomicAdd(out + b * M_ + m, 0.9f * acc[r]);
        }
    }
}

extern "C" void kernel_launch(void* const* d_in, const int* in_sizes, int n_in,
                              void* d_out, int out_size, void* d_ws, size_t ws_size,
                              hipStream_t stream) {
    const float* se    = (const float*)d_in[0];
    const int*   be    = (const int*)  d_in[1];
    const float* mlp_w = (const float*)d_in[2];
    const float* mlp_b = (const float*)d_in[3];
    const float* fk_w  = (const float*)d_in[4];
    const float* fk_b  = (const float*)d_in[5];
    float* out = (float*)d_out;
    float* ep  = (float*)d_ws;                  // event_pair [128][1536] f32
    float* pp  = ep + (size_t)B_ * 2 * E_;      // partials [KSPLIT][128][768] f32
    __bf16* apk = (__bf16*)(pp + (size_t)KSPLIT * B_ * M_);  // packed A bf16

    const int be_stride = (in_sizes[1] == B_ * 4 * 2) ? 2 : 1;

    prep<<<3584, 256, 0, stream>>>(mlp_b, fk_b, se, be, be_stride, out, ep, apk);
    fk_gemm<<<MTN * KSPLIT, 256, 0, stream>>>(apk, fk_w, pp);
    post<<<1632, 256, 0, stream>>>(pp, ep, mlp_w, out);
}

// Round 16
// 172.120 us; speedup vs baseline: 1.0564x; 1.0564x over previous
//
#include <hip/hip_runtime.h>
#include <hip/hip_bf16.h>

#define B_ 128
#define S_ 196
#define E_ 768
#define M_ 768
#define KTOT (S_*E_)            // 150528
#define BK 256                  // k per superstep
#define SS_TOTAL (KTOT/BK)      // 588
#define KSPLIT 48
#define BN 48                   // m-rows per workgroup
#define MTN (M_/BN)             // 16
#define PITCH 528               // LDS row pitch bytes (132 words -> uniform banks)
#define ZC 4                    // z-chunks in reduce

typedef __bf16 bf16x8 __attribute__((ext_vector_type(8)));
typedef __bf16 bf16x4 __attribute__((ext_vector_type(4)));
typedef float  f32x4  __attribute__((ext_vector_type(4)));

__device__ inline bf16x8 cvt8(const float* __restrict__ p) {
    float4 a = *(const float4*)p;
    float4 b = *(const float4*)(p + 4);
    bf16x8 r;
    r[0] = (__bf16)a.x; r[1] = (__bf16)a.y; r[2] = (__bf16)a.z; r[3] = (__bf16)a.w;
    r[4] = (__bf16)b.x; r[5] = (__bf16)b.y; r[6] = (__bf16)b.z; r[7] = (__bf16)b.w;
    return r;
}

// Barrier WITHOUT the implicit vmcnt(0) drain __syncthreads() carries.
__device__ inline void barrier_nodrain() {
    asm volatile("s_waitcnt lgkmcnt(0)" ::: "memory");
    __builtin_amdgcn_s_barrier();
}

// ---------------- prep: init_out | event_pool | pack_a (block-partitioned) ----
// pack_a (16x16x32 A-fragment order, as R10-R12):
//   chunk c = ((ss*8 + bt)*8 + kf)*64 + lane  holds
//   A[bt*16 + (lane&15)][ss*256 + kf*32 + (lane>>4)*8 .. +8)
__global__ void prep(const float* __restrict__ mlp_b,
                     const float* __restrict__ fk_b,
                     const float* __restrict__ A,
                     const int* __restrict__ BE, int be_stride,
                     float* __restrict__ out,
                     float* __restrict__ EP,
                     __bf16* __restrict__ Apk) {
    const int bid = blockIdx.x;
    if (bid < 384) {
        int i = bid * 256 + threadIdx.x;
        int m = i % M_;
        out[i] = 0.9f * mlp_b[m] + 0.1f * fk_b[m];
    } else if (bid < 512) {
        int b = bid - 384;
        int s1 = BE[(b*4 + 0) * be_stride];
        int e1 = BE[(b*4 + 1) * be_stride];
        int s2 = BE[(b*4 + 2) * be_stride];
        int e2 = BE[(b*4 + 3) * be_stride];
        float inv1 = 1.0f / (float)(e1 - s1);
        float inv2 = 1.0f / (float)(e2 - s2);
        for (int c = threadIdx.x; c < E_; c += 256) {
            float sum1 = 0.f, sum2 = 0.f;
            for (int s = s1; s < e1; ++s) sum1 += A[((size_t)b * S_ + s) * E_ + c];
            for (int s = s2; s < e2; ++s) sum2 += A[((size_t)b * S_ + s) * E_ + c];
            EP[b * (2*E_) + c]       = sum1 * inv1;
            EP[b * (2*E_) + E_ + c]  = sum2 * inv2;
        }
    } else {
        const int nchunk = SS_TOTAL * 8 * 8 * 64;   // 2,408,448
        for (int c = (bid - 512) * 256 + threadIdx.x; c < nchunk; c += 3072 * 256) {
            int lane = c & 63;
            int kf   = (c >> 6) & 7;
            int bt   = (c >> 9) & 7;
            int ss   = c >> 12;
            int b = bt * 16 + (lane & 15);
            int k = ss * BK + kf * 32 + (lane >> 4) * 8;
            *(bf16x8*)(Apk + (size_t)c * 8) = cvt8(A + (size_t)b * KTOT + k);
        }
    }
}

// ---------------- fk_gemm: partial[kz][b][m] ------------------------------
// 4 waves, tile 128b x 48m x 256k/ss, MFMA 16x16x32. Wave owns TWO b-tiles
// (32 rows): each B-fragment LDS read feeds 2 MFMAs -> per-wg LDS reads
// halved vs R14 (96 ds_read_b128/ss), dropping the LDS pipe below the HBM-
// fair share. W staged 1KB-per-row float4 wave loads (12 rows/wave) -> bf16
// -> LDS (PITCH 528, uniform banks). Depth-1 consume-then-reload W register
// prefetch, barrier_nodrain dbuf (R14 skeleton). A register-direct from
// packed frags (1KB single-segment loads, XCD-L2-resident via pinning).
// ~150 VGPR @ 256 thr -> 3 waves/SIMD; grid 768 = exactly 3 wgs/CU
// (LDS 152 KB) = 12 waves/CU.

#define LOAD_A(sl)                                                            \
    _Pragma("unroll")                                                         \
    for (int kf = 0; kf < 8; ++kf) {                                          \
        aT0[kf] = *(const bf16x8*)(abase0 + (size_t)(sl) * 32768 + kf * 512); \
        aT1[kf] = *(const bf16x8*)(abase1 + (size_t)(sl) * 32768 + kf * 512); \
    }

#define LOAD_W(sl)                                                            \
    _Pragma("unroll")                                                         \
    for (int i = 0; i < 12; ++i)                                              \
        w[i] = *(const float4*)(wbase + (size_t)i * KTOT + (size_t)(sl) * BK);

#define WRITE_W(buf)                                                          \
    _Pragma("unroll")                                                         \
    for (int i = 0; i < 12; ++i) {                                            \
        bf16x4 h;                                                             \
        h[0] = (__bf16)w[i].x; h[1] = (__bf16)w[i].y;                         \
        h[2] = (__bf16)w[i].z; h[3] = (__bf16)w[i].w;                         \
        *(bf16x4*)(&Wlds[buf][0] + wb + i * PITCH) = h;                       \
    }

#define COMPUTE(buf)                                                          \
    _Pragma("unroll")                                                         \
    for (int kf = 0; kf < 8; ++kf) {                                          \
        _Pragma("unroll")                                                     \
        for (int n = 0; n < 3; ++n) {                                         \
            bf16x8 wf = *(const bf16x8*)(&Wlds[buf][0] +                      \
                        (n * 16 + r16) * PITCH + kf * 64 + kg * 16);          \
            acc0[n] = __builtin_amdgcn_mfma_f32_16x16x32_bf16(aT0[kf], wf,    \
                                                              acc0[n], 0,0,0);\
            acc1[n] = __builtin_amdgcn_mfma_f32_16x16x32_bf16(aT1[kf], wf,    \
                                                              acc1[n], 0,0,0);\
        }                                                                     \
    }

__global__ __launch_bounds__(256, 3) void fk_gemm(const __bf16* __restrict__ Apk,
                                                  const float* __restrict__ W,
                                                  float* __restrict__ partial) {
    __shared__ __align__(16) char Wlds[2][BN * PITCH];  // 2 x 25,344 B

    const int wg   = blockIdx.x;        // 0..767
    const int xcd  = wg & 7;            // wg -> XCD round-robin (m09)
    const int slot = wg >> 3;           // 0..95 per-XCD sequence
    const int kz   = (slot >> 4) * 8 + xcd;  // 6 kz groups per XCD
    const int mt   = slot & 15;         // 16 mt-wgs per kz, dispatch-adjacent
    const int ss0 = (SS_TOTAL * kz) / KSPLIT;
    const int SSN = (SS_TOTAL * (kz + 1)) / KSPLIT - ss0;   // 12 or 13

    const int tid = threadIdx.x;
    const int wv  = tid >> 6;           // 0..3; b-tiles 2wv, 2wv+1
    const int lane = tid & 63;
    const int r16 = lane & 15;
    const int kg  = lane >> 4;

    const float*  wbase = W + (size_t)(mt * BN + wv * 12) * KTOT
                            + (size_t)ss0 * BK + lane * 4;
    const int     wb    = (wv * 12) * PITCH + lane * 8;
    const __bf16* abase0 = Apk + ((size_t)ss0 * 8 + 2 * wv)     * 4096 + lane * 8;
    const __bf16* abase1 = Apk + ((size_t)ss0 * 8 + 2 * wv + 1) * 4096 + lane * 8;

    f32x4 acc0[3] = {}, acc1[3] = {};
    float4 w[12];
    bf16x8 aT0[8], aT1[8];

    // prologue: stage ss0 into buf0; W(1) in flight
    LOAD_W(0)
    WRITE_W(0)
    LOAD_W(1)
    barrier_nodrain();

    int sl = 0;
    for (; sl + 1 < SSN; sl += 2) {
        // even: compute ss sl from buf0; stage W(sl+1) -> buf1
        LOAD_A(sl)
        COMPUTE(0)
        WRITE_W(1)                      // W(sl+1), loaded ~1 ss ago
        const bool more2 = (sl + 2 < SSN);
        if (more2) { LOAD_W(sl + 2) }
        barrier_nodrain();
        // odd: compute ss sl+1 from buf1; stage W(sl+2) -> buf0
        LOAD_A(sl + 1)
        COMPUTE(1)
        if (more2) {
            WRITE_W(0)                  // W(sl+2), loaded ~1 ss ago
            if (sl + 3 < SSN) { LOAD_W(sl + 3) }
            barrier_nodrain();
        }
    }
    if (SSN & 1) {  // last even ss, already staged into buf0
        LOAD_A(sl)
        COMPUTE(0)
    }

    // D layout: col = lane&15 (m), row = (lane>>4)*4 + reg (b)   [m89/m91]
    float* pz = partial + (size_t)kz * (B_ * M_);
#pragma unroll
    for (int n = 0; n < 3; ++n) {
        const int m = mt * BN + n * 16 + r16;
#pragma unroll
        for (int r = 0; r < 4; ++r) {
            const int b0 = (2 * wv) * 16 + kg * 4 + r;
            pz[(size_t)b0 * M_ + m]        = acc0[n][r];
            pz[(size_t)(b0 + 16) * M_ + m] = acc1[n][r];
        }
    }
}

// ---------------- post: reduce_k | mlp_gemm (block-partitioned) -------------
__global__ __launch_bounds__(256) void post(const float* __restrict__ pp,
                                            const float* __restrict__ EP,
                                            const float* __restrict__ Wm,
                                            float* __restrict__ out) {
    const int bid = blockIdx.x;
    if (bid < 1536) {
        int t = bid * 256 + threadIdx.x;
        int i = t % (B_ * M_);
        int zc = t / (B_ * M_);
        float s = 0.f;
#pragma unroll
        for (int z = zc * (KSPLIT / ZC); z < (zc + 1) * (KSPLIT / ZC); ++z)
            s += pp[(size_t)z * (B_ * M_) + i];
        atomicAdd(out + i, 0.1f * s);
    } else {
        const int wid   = ((bid - 1536) * 256 + threadIdx.x) >> 6;  // 0..383
        const int lane  = threadIdx.x & 63;
        const int bt    = wid & 7;
        const int mt    = wid >> 3;
        const int row16 = lane & 15;
        const int kgrp  = lane >> 4;
        const float* Arow = EP + (size_t)(bt*16 + row16) * (2*E_);
        const float* Brow = Wm + (size_t)(mt*16 + row16) * (2*E_);
        f32x4 acc = {};
        for (int k0 = 0; k0 < 2*E_; k0 += 32) {
            bf16x8 af = cvt8(Arow + k0 + kgrp*8);
            bf16x8 bv = cvt8(Brow + k0 + kgrp*8);
            acc = __builtin_amdgcn_mfma_f32_16x16x32_bf16(af, bv, acc, 0, 0, 0);
        }
        const int m = mt*16 + row16;
#pragma unroll
        for (int r = 0; r < 4; ++r) {
            const int b = bt*16 + kgrp*4 + r;
            atomicAdd(out + b * M_ + m, 0.9f * acc[r]);
        }
    }
}

extern "C" void kernel_launch(void* const* d_in, const int* in_sizes, int n_in,
                              void* d_out, int out_size, void* d_ws, size_t ws_size,
                              hipStream_t stream) {
    const float* se    = (const float*)d_in[0];
    const int*   be    = (const int*)  d_in[1];
    const float* mlp_w = (const float*)d_in[2];
    const float* mlp_b = (const float*)d_in[3];
    const float* fk_w  = (const float*)d_in[4];
    const float* fk_b  = (const float*)d_in[5];
    float* out = (float*)d_out;
    float* ep  = (float*)d_ws;                  // event_pair [128][1536] f32
    float* pp  = ep + (size_t)B_ * 2 * E_;      // partials [KSPLIT][128][768] f32
    __bf16* apk = (__bf16*)(pp + (size_t)KSPLIT * B_ * M_);  // packed A bf16

    const int be_stride = (in_sizes[1] == B_ * 4 * 2) ? 2 : 1;

    prep<<<3584, 256, 0, stream>>>(mlp_b, fk_b, se, be, be_stride, out, ep, apk);
    fk_gemm<<<MTN * KSPLIT, 256, 0, stream>>>(apk, fk_w, pp);
    post<<<1632, 256, 0, stream>>>(pp, ep, mlp_w, out);
}